// Round 9
// baseline (126.113 us; speedup 1.0000x reference)
//
#include <hip/hip_runtime.h>
#include <math.h>

#define F_    16
#define NV_   4096
#define NT_   512
#define M_    4096
#define PPF_  (NV_ + NT_)        // 4608 points per frame
#define NPTS_ (F_ * PPF_)        // 73728 total points
#define SCALE_INV 10.0f          // 1 / 0.1

#define TPB   256
#define PTSB  32                 // 144 blocks/frame (no straddle); grid 2304 = 9 blocks/CU
#define NBLK  (NPTS_ / PTSB)     // 2304
#define NGR   32                 // model groups (g = t>>3); 8 point-lanes per group
#define MPG   (M_ / NGR)         // 128 models per group per thread
#define PPL   4                  // points per lane (8 lanes x 4 = 32)

typedef float v2f __attribute__((ext_vector_type(2)));
typedef float v4f __attribute__((ext_vector_type(4)));

// ---------------------------------------------------------------- pose math
__device__ inline void rot_from_omega(float ox, float oy, float oz, float dt,
                                      float* R) {
    // R = I + sin(theta*dt)*S + (1-cos(theta*dt))*S^2,  S = skew(omega/max(theta,1e-8))
    float theta = sqrtf(ox * ox + oy * oy + oz * oz);
    float inv = 1.0f / fmaxf(theta, 1e-8f);
    float ax = ox * inv, ay = oy * inv, az = oz * inv;
    float s = sinf(theta * dt);
    float c = 1.0f - cosf(theta * dt);
    R[0] = 1.0f - c * (ay * ay + az * az);
    R[1] = -s * az + c * ax * ay;
    R[2] =  s * ay + c * ax * az;
    R[3] =  s * az + c * ax * ay;
    R[4] = 1.0f - c * (ax * ax + az * az);
    R[5] = -s * ax + c * ay * az;
    R[6] = -s * ay + c * ax * az;
    R[7] =  s * ax + c * ay * az;
    R[8] = 1.0f - c * (ax * ax + ay * ay);
}

// ---------------------------------------------------------------- packed distance core
// 2 models x 2 point-pairs: 12 v_pk_fma_f32 + 4 v_min3. op_sel encodings are
// byte-identical to the r6/r7/r8 numerically-proven ones:
//   z-stage acc = fma(-2gz, z, w); y-stage += -2gy*y; x-stage += -2gx*x.
__device__ __forceinline__ void pkdist1(v2f qa01, v2f qa23, v2f qb01, v2f qb23,
                                        v2f c0p0, v2f c0p1, v2f c1p0, v2f c1p1,
                                        v2f c2p0, v2f c2p1, float* dm) {
    v2f A0, A1, B0, B1;
    asm("v_pk_fma_f32 %0, %5, %12, %5 op_sel:[0,0,1] op_sel_hi:[0,1,1]\n\t"
        "v_pk_fma_f32 %1, %5, %13, %5 op_sel:[0,0,1] op_sel_hi:[0,1,1]\n\t"
        "v_pk_fma_f32 %2, %7, %12, %7 op_sel:[0,0,1] op_sel_hi:[0,1,1]\n\t"
        "v_pk_fma_f32 %3, %7, %13, %7 op_sel:[0,0,1] op_sel_hi:[0,1,1]\n\t"
        "v_pk_fma_f32 %0, %4, %10, %0 op_sel:[1,0,0] op_sel_hi:[1,1,1]\n\t"
        "v_pk_fma_f32 %1, %4, %11, %1 op_sel:[1,0,0] op_sel_hi:[1,1,1]\n\t"
        "v_pk_fma_f32 %2, %6, %10, %2 op_sel:[1,0,0] op_sel_hi:[1,1,1]\n\t"
        "v_pk_fma_f32 %3, %6, %11, %3 op_sel:[1,0,0] op_sel_hi:[1,1,1]\n\t"
        "v_pk_fma_f32 %0, %4, %8, %0  op_sel:[0,0,0] op_sel_hi:[0,1,1]\n\t"
        "v_pk_fma_f32 %1, %4, %9, %1  op_sel:[0,0,0] op_sel_hi:[0,1,1]\n\t"
        "v_pk_fma_f32 %2, %6, %8, %2  op_sel:[0,0,0] op_sel_hi:[0,1,1]\n\t"
        "v_pk_fma_f32 %3, %6, %9, %3  op_sel:[0,0,0] op_sel_hi:[0,1,1]"
        : "=&v"(A0), "=&v"(A1), "=&v"(B0), "=&v"(B1)
        : "v"(qa01), "v"(qa23), "v"(qb01), "v"(qb23),
          "v"(c0p0), "v"(c0p1), "v"(c1p0), "v"(c1p1), "v"(c2p0), "v"(c2p1));
    dm[0] = fminf(fminf(A0.x, B0.x), dm[0]);
    dm[1] = fminf(fminf(A0.y, B0.y), dm[1]);
    dm[2] = fminf(fminf(A1.x, B1.x), dm[2]);
    dm[3] = fminf(fminf(A1.y, B1.y), dm[3]);
}

// ---------------------------------------------------------------- prep (ws is free: poison fill is unconditional)
__global__ void prep_kernel(const float* __restrict__ state,
                            const float* __restrict__ phys,
                            const float* __restrict__ dts,
                            const float* __restrict__ model,
                            float* __restrict__ ws_pose,
                            float4* __restrict__ ws_feat) {
    const int b = blockIdx.x, t = threadIdx.x;
    if (b == 0) {
        __shared__ float sRs[F_ * 9];
        __shared__ float sdt[F_ * 3];
        if (t < F_) {
            float ox, oy, oz, dt;
            if (t == 0) { ox = state[3]; oy = state[4]; oz = state[5]; dt = 1.0f; }
            else        { ox = phys[t * 12 + 9]; oy = phys[t * 12 + 10];
                          oz = phys[t * 12 + 11]; dt = dts[t]; }
            float Rs[9];
            rot_from_omega(ox, oy, oz, dt, Rs);
            for (int j = 0; j < 9; ++j) sRs[t * 9 + j] = Rs[j];
            if (t > 0) {
                sdt[t * 3 + 0] = phys[t * 12 + 6] * dt;
                sdt[t * 3 + 1] = phys[t * 12 + 7] * dt;
                sdt[t * 3 + 2] = phys[t * 12 + 8] * dt;
            }
        }
        if (t == 0) {   // same wave as the writers above -> lockstep-ordered
            float R[9];
            for (int j = 0; j < 9; ++j) R[j] = sRs[j];
            float tr[3] = {state[0], state[1], state[2]};
            for (int i = 0; i < F_; ++i) {
                if (i > 0) {
                    tr[0] += sdt[i * 3 + 0];
                    tr[1] += sdt[i * 3 + 1];
                    tr[2] += sdt[i * 3 + 2];
                    float Rn[9];
                    const float* Rsp = sRs + i * 9;
                    for (int r = 0; r < 3; ++r)
                        for (int c2 = 0; c2 < 3; ++c2)
                            Rn[r * 3 + c2] = Rsp[r * 3 + 0] * R[0 + c2] +
                                             Rsp[r * 3 + 1] * R[3 + c2] +
                                             Rsp[r * 3 + 2] * R[6 + c2];
                    for (int j = 0; j < 9; ++j) R[j] = Rn[j];
                }
                float* o = ws_pose + i * 12;
                o[0] = tr[0]; o[1] = tr[1]; o[2] = tr[2];
                for (int j = 0; j < 9; ++j) o[3 + j] = R[j] * SCALE_INV;
            }
        }
    } else {
        const int id = (b - 1) * 256 + t;   // 0..4095 linear
        float gx = model[id * 3 + 0], gy = model[id * 3 + 1], gz = model[id * 3 + 2];
        ws_feat[id] = make_float4(-2.0f * gx, -2.0f * gy, -2.0f * gz,
                                  gx * gx + gy * gy + gz * gz);
    }
}

// ---------------------------------------------------------------- main kernel
// Recalibrated model (r5/r7 VALUBusy fits): effective clock ~1.2 GHz; prior
// versions sat AT their VALU-issue floors, wall excess = empty issue slots
// (latency + barrier convoys at 4 waves/SIMD). This version: 8 waves/SIMD
// (VGPR<=64 via launch_bounds(256,8)), ZERO LDS / ZERO barriers in the main
// loop (models via wave-uniform global_load_dwordx4 from L1/L2-resident
// ws_feat), poses from ws, single atomic per block, 2 launches total.
__global__ __launch_bounds__(TPB, 8) void chamfer_main(
    const float* __restrict__ vis, const float* __restrict__ tac,
    const float* __restrict__ ws_pose, const float4* __restrict__ ws_feat,
    float* __restrict__ out) {
    __shared__ float spose[F_ * 12];
    __shared__ float sdm[PTSB][NGR + 1];    // 4.2 KB (+1 pad: conflict-free col reads)

    const int t  = threadIdx.x;
    const int g  = t >> 3;                  // model group 0..31
    const int pl = t & 7;                   // point-lane 0..7 (4 points each)
    const int f  = blockIdx.x / 144;        // 144 blocks/frame, frame-uniform
    const int lbase = (blockIdx.x - f * 144) * PTSB;

    if (t < F_ * 12) spose[t] = ws_pose[t];
    __syncthreads();

    // ---- transform my 4 points into 2 packed pairs ----
    v2f c0p[2], c1p[2], c2p[2];
    float cn[PPL], dm[PPL];
    {
        const float* ps = spose + f * 12;
        float xx[PPL], yy[PPL], zz[PPL];
#pragma unroll
        for (int k = 0; k < PPL; ++k) {
            int loc = lbase + pl * PPL + k;
            const float* p = (loc < NV_) ? (vis + ((size_t)f * NV_ + loc) * 3)
                                         : (tac + ((size_t)f * NT_ + (loc - NV_)) * 3);
            float d0 = p[0] - ps[0], d1 = p[1] - ps[1], d2 = p[2] - ps[2];
            const float* R = ps + 3;
            float x = d0 * R[0] + d1 * R[3] + d2 * R[6];
            float y = d0 * R[1] + d1 * R[4] + d2 * R[7];
            float z = d0 * R[2] + d1 * R[5] + d2 * R[8];
            xx[k] = x; yy[k] = y; zz[k] = z;
            cn[k] = x * x + y * y + z * z;
            dm[k] = 3.4e38f;
        }
#pragma unroll
        for (int j = 0; j < 2; ++j) {
            c0p[j] = (v2f){xx[2 * j], xx[2 * j + 1]};
            c1p[j] = (v2f){yy[2 * j], yy[2 * j + 1]};
            c2p[j] = (v2f){zz[2 * j], zz[2 * j + 1]};
        }
    }

    // ---- main loop: 128 models, no LDS, no barriers; wave-uniform 16B loads ----
    const v4f* fg = (const v4f*)(ws_feat + (size_t)g * MPG);
#pragma unroll 2
    for (int m = 0; m < MPG; m += 2) {
        v4f ga = fg[m];                     // {-2gx,-2gy,-2gz,w}: one request/wave
        v4f gb = fg[m + 1];
        pkdist1(__builtin_shufflevector(ga, ga, 0, 1),
                __builtin_shufflevector(ga, ga, 2, 3),
                __builtin_shufflevector(gb, gb, 0, 1),
                __builtin_shufflevector(gb, gb, 2, 3),
                c0p[0], c0p[1], c1p[0], c1p[1], c2p[0], c2p[1], dm);
    }

    // ---- cross-group min (32 groups) + weighted block sum + one atomic ----
#pragma unroll
    for (int k = 0; k < PPL; ++k) sdm[pl * PPL + k][g] = dm[k] + cn[k];
    __syncthreads();

    if (t < 64) {                           // exactly wave 0
        float v = 0.0f;
        if (t < PTSB) {
            const float* row = sdm[t];
            float mn = row[0];
#pragma unroll 8
            for (int i = 1; i < NGR; ++i) mn = fminf(mn, row[i]);
            const int loc = lbase + t;
            const float w = (loc < NV_) ? (1.0f / NV_) : (0.1f / NT_);
            v = mn * w;
        }
#pragma unroll
        for (int off = 32; off > 0; off >>= 1) v += __shfl_down(v, off);
        if (t == 0) atomicAdd(out, v);
    }
}

// ---------------------------------------------------------------- safety fallback (ws too small; never per evidence)
__global__ __launch_bounds__(TPB) void chamfer_fb(
    const float* __restrict__ state, const float* __restrict__ model,
    const float* __restrict__ vis, const float* __restrict__ tac,
    const float* __restrict__ phys, const float* __restrict__ dts,
    float* __restrict__ out) {
    __shared__ float sw[4];
    const int pt = blockIdx.x * TPB + threadIdx.x;
    const int f = pt / PPF_, loc = pt - f * PPF_;
    float R[9], tr[3] = {state[0], state[1], state[2]};
    rot_from_omega(state[3], state[4], state[5], 1.0f, R);
    for (int i = 1; i <= f; ++i) {
        float dt = dts[i];
        tr[0] += phys[i * 12 + 6] * dt;
        tr[1] += phys[i * 12 + 7] * dt;
        tr[2] += phys[i * 12 + 8] * dt;
        float Rs[9], Rn[9];
        rot_from_omega(phys[i * 12 + 9], phys[i * 12 + 10], phys[i * 12 + 11], dt, Rs);
        for (int r = 0; r < 3; ++r)
            for (int c2 = 0; c2 < 3; ++c2)
                Rn[r * 3 + c2] = Rs[r * 3 + 0] * R[0 + c2] +
                                 Rs[r * 3 + 1] * R[3 + c2] +
                                 Rs[r * 3 + 2] * R[6 + c2];
        for (int j = 0; j < 9; ++j) R[j] = Rn[j];
    }
    for (int j = 0; j < 9; ++j) R[j] *= SCALE_INV;
    const float* p = (loc < NV_) ? (vis + ((size_t)f * NV_ + loc) * 3)
                                 : (tac + ((size_t)f * NT_ + (loc - NV_)) * 3);
    float d0 = p[0] - tr[0], d1 = p[1] - tr[1], d2 = p[2] - tr[2];
    float x = d0 * R[0] + d1 * R[3] + d2 * R[6];
    float y = d0 * R[1] + d1 * R[4] + d2 * R[7];
    float z = d0 * R[2] + d1 * R[5] + d2 * R[8];
    float cnv = x * x + y * y + z * z;
    float mn = 3.4e38f;
    for (int i = 0; i < M_; ++i) {
        float gx = model[i * 3], gy = model[i * 3 + 1], gz = model[i * 3 + 2];
        float gn = gx * gx + gy * gy + gz * gz;
        float dd = fmaf(-2.0f * gx, x, fmaf(-2.0f * gy, y, fmaf(-2.0f * gz, z, gn)));
        mn = fminf(mn, dd);
    }
    float w = (loc < NV_) ? (1.0f / NV_) : (0.1f / NT_);
    float v = (mn + cnv) * w;
    for (int off = 32; off > 0; off >>= 1) v += __shfl_down(v, off);
    if ((threadIdx.x & 63) == 0) sw[threadIdx.x >> 6] = v;
    __syncthreads();
    if (threadIdx.x == 0) atomicAdd(out, sw[0] + sw[1] + sw[2] + sw[3]);
}

// ---------------------------------------------------------------- launch
extern "C" void kernel_launch(void* const* d_in, const int* in_sizes, int n_in,
                              void* d_out, int out_size, void* d_ws, size_t ws_size,
                              hipStream_t stream) {
    const float* state = (const float*)d_in[0];   // (6,)
    const float* model = (const float*)d_in[1];   // (M,3)
    const float* vis   = (const float*)d_in[2];   // (F,NV,3)
    const float* tac   = (const float*)d_in[3];   // (F,NT,3)
    const float* phys  = (const float*)d_in[4];   // (F,12)
    const float* dts   = (const float*)d_in[5];   // (F,)
    float* out = (float*)d_out;

    const size_t NEED = 1024 + (size_t)M_ * sizeof(float4);  // 66.6 KB
    hipMemsetAsync(out, 0, sizeof(float), stream);
    if (ws_size >= NEED) {
        float*  ws_pose = (float*)d_ws;
        float4* ws_feat = (float4*)((char*)d_ws + 1024);
        prep_kernel<<<17, 256, 0, stream>>>(state, phys, dts, model, ws_pose, ws_feat);
        chamfer_main<<<NBLK, TPB, 0, stream>>>(vis, tac, ws_pose, ws_feat, out);
    } else {
        chamfer_fb<<<NPTS_ / TPB, TPB, 0, stream>>>(state, model, vis, tac, phys,
                                                    dts, out);
    }
}

// Round 10
// 96.415 us; speedup vs baseline: 1.3080x; 1.3080x over previous
//
#include <hip/hip_runtime.h>
#include <math.h>

#define F_    16
#define NV_   4096
#define NT_   512
#define M_    4096
#define PPF_  (NV_ + NT_)        // 4608 points per frame
#define NPTS_ (F_ * PPF_)        // 73728 total points
#define SCALE_INV 10.0f          // 1 / 0.1

#define TPB   256
#define PTSB  96                 // 48 blocks/frame (no straddle); 768 blocks = 3/CU EXACT (no tail)
#define NBLK  (NPTS_ / PTSB)     // 768
#define NG    32                 // model groups (g = t>>3, 8 lanes each)
#define MPG   (M_ / NG)          // 128 models per group
#define CHM   32                 // models per group per chunk
#define NCH   (MPG / CHM)        // 4 chunks
#define FS    33                 // v4f stride/group: (g*33+m)&7 = (g+m)&7 -> 8 disjoint bank-quads/wave
#define PPL   12                 // points per lane (8 point-lanes x 12 = 96)
#define NPR   6                  // f32 pairs per lane

typedef float v2f __attribute__((ext_vector_type(2)));
typedef float v4f __attribute__((ext_vector_type(4)));

// ---------------------------------------------------------------- pose math
__device__ inline void rot_from_omega(float ox, float oy, float oz, float dt,
                                      float* R) {
    // R = I + sin(theta*dt)*S + (1-cos(theta*dt))*S^2,  S = skew(omega/max(theta,1e-8))
    float theta = sqrtf(ox * ox + oy * oy + oz * oz);
    float inv = 1.0f / fmaxf(theta, 1e-8f);
    float ax = ox * inv, ay = oy * inv, az = oz * inv;
    float s = sinf(theta * dt);
    float c = 1.0f - cosf(theta * dt);
    R[0] = 1.0f - c * (ay * ay + az * az);
    R[1] = -s * az + c * ax * ay;
    R[2] =  s * ay + c * ax * az;
    R[3] =  s * az + c * ax * ay;
    R[4] = 1.0f - c * (ax * ax + az * az);
    R[5] = -s * ax + c * ay * az;
    R[6] = -s * ay + c * ax * az;
    R[7] =  s * ax + c * ay * az;
    R[8] = 1.0f - c * (ax * ax + ay * ay);
}

// ---------------------------------------------------------------- packed distance core (r7-proven, absmax 0)
// 2 models (A,B) x 3 point-pairs: 18 v_pk_fma_f32 + 6 v_min3.
// z-stage acc = fma(-2gz, z, w); y-stage += -2gy*y; x-stage += -2gx*x.
__device__ __forceinline__ void dist6(v2f qa01, v2f qa23, v2f qb01, v2f qb23,
                                      v2f c0a, v2f c0b, v2f c0c,
                                      v2f c1a, v2f c1b, v2f c1c,
                                      v2f c2a, v2f c2b, v2f c2c, float* dmp) {
    v2f A0, A1, A2, B0, B1, B2;
    asm("v_pk_fma_f32 %0, %7, %16, %7 op_sel:[0,0,1] op_sel_hi:[0,1,1]\n\t"
        "v_pk_fma_f32 %1, %7, %17, %7 op_sel:[0,0,1] op_sel_hi:[0,1,1]\n\t"
        "v_pk_fma_f32 %2, %7, %18, %7 op_sel:[0,0,1] op_sel_hi:[0,1,1]\n\t"
        "v_pk_fma_f32 %3, %9, %16, %9 op_sel:[0,0,1] op_sel_hi:[0,1,1]\n\t"
        "v_pk_fma_f32 %4, %9, %17, %9 op_sel:[0,0,1] op_sel_hi:[0,1,1]\n\t"
        "v_pk_fma_f32 %5, %9, %18, %9 op_sel:[0,0,1] op_sel_hi:[0,1,1]\n\t"
        "v_pk_fma_f32 %0, %6, %13, %0 op_sel:[1,0,0] op_sel_hi:[1,1,1]\n\t"
        "v_pk_fma_f32 %1, %6, %14, %1 op_sel:[1,0,0] op_sel_hi:[1,1,1]\n\t"
        "v_pk_fma_f32 %2, %6, %15, %2 op_sel:[1,0,0] op_sel_hi:[1,1,1]\n\t"
        "v_pk_fma_f32 %3, %8, %13, %3 op_sel:[1,0,0] op_sel_hi:[1,1,1]\n\t"
        "v_pk_fma_f32 %4, %8, %14, %4 op_sel:[1,0,0] op_sel_hi:[1,1,1]\n\t"
        "v_pk_fma_f32 %5, %8, %15, %5 op_sel:[1,0,0] op_sel_hi:[1,1,1]\n\t"
        "v_pk_fma_f32 %0, %6, %10, %0 op_sel:[0,0,0] op_sel_hi:[0,1,1]\n\t"
        "v_pk_fma_f32 %1, %6, %11, %1 op_sel:[0,0,0] op_sel_hi:[0,1,1]\n\t"
        "v_pk_fma_f32 %2, %6, %12, %2 op_sel:[0,0,0] op_sel_hi:[0,1,1]\n\t"
        "v_pk_fma_f32 %3, %8, %10, %3 op_sel:[0,0,0] op_sel_hi:[0,1,1]\n\t"
        "v_pk_fma_f32 %4, %8, %11, %4 op_sel:[0,0,0] op_sel_hi:[0,1,1]\n\t"
        "v_pk_fma_f32 %5, %8, %12, %5 op_sel:[0,0,0] op_sel_hi:[0,1,1]"
        : "=&v"(A0), "=&v"(A1), "=&v"(A2), "=&v"(B0), "=&v"(B1), "=&v"(B2)
        : "v"(qa01), "v"(qa23), "v"(qb01), "v"(qb23),
          "v"(c0a), "v"(c0b), "v"(c0c),
          "v"(c1a), "v"(c1b), "v"(c1c),
          "v"(c2a), "v"(c2b), "v"(c2c));
    dmp[0] = fminf(fminf(A0.x, B0.x), dmp[0]);
    dmp[1] = fminf(fminf(A0.y, B0.y), dmp[1]);
    dmp[2] = fminf(fminf(A1.x, B1.x), dmp[2]);
    dmp[3] = fminf(fminf(A1.y, B1.y), dmp[3]);
    dmp[4] = fminf(fminf(A2.x, B2.x), dmp[4]);
    dmp[5] = fminf(fminf(A2.y, B2.y), dmp[5]);
}

// ---------------------------------------------------------------- fused kernel
// R10 = R3 frame (best measured: single kernel, 768 blocks = 3/CU exact,
// conflict-free LDS broadcast, reg-prefetch staging, per-thread pose) with
// ONLY the inner loop swapped scalar->pk_fma (r6/r7-proven encoding).
// Clean A/B: every other byte of structure matches round 3.
__global__ __launch_bounds__(TPB, 3) void chamfer_one(
    const float* __restrict__ state, const float* __restrict__ model,
    const float* __restrict__ vis, const float* __restrict__ tac,
    const float* __restrict__ phys, const float* __restrict__ dts,
    float* __restrict__ out) {
    __shared__ v4f   feat[NG * FS];         // 16.9 KB model features {-2g, |g|^2}
    __shared__ float sdm[PTSB][NG + 1];     // 12.7 KB per-point per-group mins (+1 pad)
    __shared__ float sw[2];

    const int t  = threadIdx.x;
    const int g  = t >> 3;                  // model group 0..31
    const int m0 = t & 7;
    const int pl = t & 7;                   // point-lane 0..7 (12 points each)
    const int f  = (blockIdx.x * PTSB) / PPF_;          // block-uniform
    const int lbase = blockIdx.x * PTSB - f * PPF_;

    // ---- stage chunk 0 early (hide under pose math) ----
#pragma unroll
    for (int j2 = 0; j2 < 4; ++j2) {
        int id = g * MPG + m0 + 8 * j2;
        float gx = model[id * 3 + 0], gy = model[id * 3 + 1], gz = model[id * 3 + 2];
        feat[g * FS + m0 + 8 * j2] =
            (v4f){-2.0f * gx, -2.0f * gy, -2.0f * gz, gx * gx + gy * gy + gz * gz};
    }

    // ---- pose for frame f, per-thread (uniform f -> no divergence; identical
    // op order to the reference scan) ----
    float R[9], tr[3];
    {
        tr[0] = state[0]; tr[1] = state[1]; tr[2] = state[2];
        rot_from_omega(state[3], state[4], state[5], 1.0f, R);
        for (int i = 1; i <= f; ++i) {
            float dt = dts[i];
            tr[0] += phys[i * 12 + 6] * dt;
            tr[1] += phys[i * 12 + 7] * dt;
            tr[2] += phys[i * 12 + 8] * dt;
            float Rs[9];
            rot_from_omega(phys[i * 12 + 9], phys[i * 12 + 10], phys[i * 12 + 11], dt, Rs);
            float Rn[9];
            for (int r = 0; r < 3; ++r)
                for (int c2 = 0; c2 < 3; ++c2)
                    Rn[r * 3 + c2] = Rs[r * 3 + 0] * R[0 + c2] +
                                     Rs[r * 3 + 1] * R[3 + c2] +
                                     Rs[r * 3 + 2] * R[6 + c2];
            for (int j = 0; j < 9; ++j) R[j] = Rn[j];
        }
        for (int j = 0; j < 9; ++j) R[j] *= SCALE_INV;  // fold 1/SCALE
    }

    // ---- transform my 12 points into 6 packed pairs ----
    v2f c0p[NPR], c1p[NPR], c2p[NPR];
    float cn[PPL], dm[PPL];
#pragma unroll
    for (int k = 0; k < PPL; ++k) {
        int loc = lbase + pl * PPL + k;
        const float* p = (loc < NV_) ? (vis + ((size_t)f * NV_ + loc) * 3)
                                     : (tac + ((size_t)f * NT_ + (loc - NV_)) * 3);
        float d0 = p[0] - tr[0], d1 = p[1] - tr[1], d2 = p[2] - tr[2];
        float x = d0 * R[0] + d1 * R[3] + d2 * R[6];
        float y = d0 * R[1] + d1 * R[4] + d2 * R[7];
        float z = d0 * R[2] + d1 * R[5] + d2 * R[8];
        cn[k] = x * x + y * y + z * z;
        dm[k] = 3.4e38f;
        if (k & 1) { c0p[k >> 1].y = x; c1p[k >> 1].y = y; c2p[k >> 1].y = z; }
        else       { c0p[k >> 1].x = x; c1p[k >> 1].x = y; c2p[k >> 1].x = z; }
    }
    __syncthreads();

    // ---- main loop: 4 chunks x 32 models/group; reg-prefetch next chunk ----
    for (int c = 0; c < NCH; ++c) {
        float mx[4], my[4], mz[4];
        if (c + 1 < NCH) {                  // issue next chunk's loads first
#pragma unroll
            for (int j2 = 0; j2 < 4; ++j2) {
                int id = g * MPG + (c + 1) * CHM + m0 + 8 * j2;
                mx[j2] = model[id * 3 + 0];
                my[j2] = model[id * 3 + 1];
                mz[j2] = model[id * 3 + 2];
            }
        }
        const v4f* fb = &feat[g * FS];
#pragma unroll 4
        for (int m = 0; m < CHM; m += 2) {
            v4f ga = fb[m];                 // 8 distinct addrs/wave, disjoint quads
            v4f gb = fb[m + 1];
            v2f qa01 = (v2f){ga.x, ga.y}, qa23 = (v2f){ga.z, ga.w};
            v2f qb01 = (v2f){gb.x, gb.y}, qb23 = (v2f){gb.z, gb.w};
            dist6(qa01, qa23, qb01, qb23, c0p[0], c0p[1], c0p[2],
                  c1p[0], c1p[1], c1p[2], c2p[0], c2p[1], c2p[2], dm);
            dist6(qa01, qa23, qb01, qb23, c0p[3], c0p[4], c0p[5],
                  c1p[3], c1p[4], c1p[5], c2p[3], c2p[4], c2p[5], dm + 6);
        }
        __syncthreads();                    // all reads of chunk c done
        if (c + 1 < NCH) {
#pragma unroll
            for (int j2 = 0; j2 < 4; ++j2) {
                feat[g * FS + m0 + 8 * j2] =
                    (v4f){-2.0f * mx[j2], -2.0f * my[j2], -2.0f * mz[j2],
                          mx[j2] * mx[j2] + my[j2] * my[j2] + mz[j2] * mz[j2]};
            }
            __syncthreads();                // chunk c+1 staged
        }
    }

    // ---- combine 32 group-partials per point, weight, block-sum, one atomic ----
#pragma unroll
    for (int k = 0; k < PPL; ++k) sdm[pl * PPL + k][g] = dm[k] + cn[k];
    __syncthreads();

    float v = 0.0f;
    if (t < PTSB) {
        const float* row = sdm[t];
        float mn = row[0];
#pragma unroll
        for (int i = 1; i < NG; ++i) mn = fminf(mn, row[i]);
        const int loc = lbase + t;
        const float w = (loc < NV_) ? (1.0f / NV_) : (0.1f / NT_);
        v = mn * w;
    }
    if (t < 128) {
#pragma unroll
        for (int off = 32; off > 0; off >>= 1) v += __shfl_down(v, off);
        if ((t & 63) == 0) sw[t >> 6] = v;
    }
    __syncthreads();
    if (t == 0) atomicAdd(out, sw[0] + sw[1]);
}

// ---------------------------------------------------------------- launch
// d_ws unused: single fused kernel (multi-kernel structures consistently lost
// to launch overhead, r8/r9); the 256MB ws poison fill runs unconditionally.
extern "C" void kernel_launch(void* const* d_in, const int* in_sizes, int n_in,
                              void* d_out, int out_size, void* d_ws, size_t ws_size,
                              hipStream_t stream) {
    const float* state = (const float*)d_in[0];   // (6,)
    const float* model = (const float*)d_in[1];   // (M,3)
    const float* vis   = (const float*)d_in[2];   // (F,NV,3)
    const float* tac   = (const float*)d_in[3];   // (F,NT,3)
    const float* phys  = (const float*)d_in[4];   // (F,12)
    const float* dts   = (const float*)d_in[5];   // (F,)
    float* out = (float*)d_out;
    (void)d_ws; (void)ws_size;

    hipMemsetAsync(out, 0, sizeof(float), stream);
    chamfer_one<<<NBLK, TPB, 0, stream>>>(state, model, vis, tac, phys, dts, out);
}

// Round 11
// 96.332 us; speedup vs baseline: 1.3092x; 1.0009x over previous
//
#include <hip/hip_runtime.h>
#include <math.h>

#define F_    16
#define NV_   4096
#define NT_   512
#define M_    4096
#define PPF_  (NV_ + NT_)        // 4608 points per frame
#define NPTS_ (F_ * PPF_)        // 73728 total points
#define SCALE_INV 10.0f          // 1 / 0.1

#define TPB   256
#define PTSB  96                 // 48 blocks/frame (no straddle); 768 blocks = 3/CU EXACT (no tail)
#define NBLK  (NPTS_ / PTSB)     // 768
#define NG    32                 // model groups (g = t>>3, 8 lanes each)
#define MPG   (M_ / NG)          // 128 models per group
#define CHM   32                 // models per group per chunk
#define NCH   (MPG / CHM)        // 4 chunks
#define FS    33                 // v4f stride/group: quad(g,m) = (g+m)&7 -> parity pair spans 2 quads, 2-way = free
#define PPL   12                 // points per lane (8 point-lanes x 12 = 96)
#define NPR   6                  // f32 pairs per lane

typedef float v2f __attribute__((ext_vector_type(2)));
typedef float v4f __attribute__((ext_vector_type(4)));

// ---------------------------------------------------------------- pose math
__device__ inline void rot_from_omega(float ox, float oy, float oz, float dt,
                                      float* R) {
    // R = I + sin(theta*dt)*S + (1-cos(theta*dt))*S^2,  S = skew(omega/max(theta,1e-8))
    float theta = sqrtf(ox * ox + oy * oy + oz * oz);
    float inv = 1.0f / fmaxf(theta, 1e-8f);
    float ax = ox * inv, ay = oy * inv, az = oz * inv;
    float s = sinf(theta * dt);
    float c = 1.0f - cosf(theta * dt);
    R[0] = 1.0f - c * (ay * ay + az * az);
    R[1] = -s * az + c * ax * ay;
    R[2] =  s * ay + c * ax * az;
    R[3] =  s * az + c * ax * ay;
    R[4] = 1.0f - c * (ax * ax + az * az);
    R[5] = -s * ax + c * ay * az;
    R[6] = -s * ay + c * ax * az;
    R[7] =  s * ax + c * ay * az;
    R[8] = 1.0f - c * (ax * ax + ay * ay);
}

// ---------------------------------------------------------------- packed distance core (r7/r10-proven, absmax 0)
// 2 models (A,B) x 3 point-pairs: 18 v_pk_fma_f32 + 6 v_min3.
// z-stage acc = fma(-2gz, z, w); y-stage += -2gy*y; x-stage += -2gx*x.
__device__ __forceinline__ void dist6(v2f qa01, v2f qa23, v2f qb01, v2f qb23,
                                      v2f c0a, v2f c0b, v2f c0c,
                                      v2f c1a, v2f c1b, v2f c1c,
                                      v2f c2a, v2f c2b, v2f c2c, float* dmp) {
    v2f A0, A1, A2, B0, B1, B2;
    asm("v_pk_fma_f32 %0, %7, %16, %7 op_sel:[0,0,1] op_sel_hi:[0,1,1]\n\t"
        "v_pk_fma_f32 %1, %7, %17, %7 op_sel:[0,0,1] op_sel_hi:[0,1,1]\n\t"
        "v_pk_fma_f32 %2, %7, %18, %7 op_sel:[0,0,1] op_sel_hi:[0,1,1]\n\t"
        "v_pk_fma_f32 %3, %9, %16, %9 op_sel:[0,0,1] op_sel_hi:[0,1,1]\n\t"
        "v_pk_fma_f32 %4, %9, %17, %9 op_sel:[0,0,1] op_sel_hi:[0,1,1]\n\t"
        "v_pk_fma_f32 %5, %9, %18, %9 op_sel:[0,0,1] op_sel_hi:[0,1,1]\n\t"
        "v_pk_fma_f32 %0, %6, %13, %0 op_sel:[1,0,0] op_sel_hi:[1,1,1]\n\t"
        "v_pk_fma_f32 %1, %6, %14, %1 op_sel:[1,0,0] op_sel_hi:[1,1,1]\n\t"
        "v_pk_fma_f32 %2, %6, %15, %2 op_sel:[1,0,0] op_sel_hi:[1,1,1]\n\t"
        "v_pk_fma_f32 %3, %8, %13, %3 op_sel:[1,0,0] op_sel_hi:[1,1,1]\n\t"
        "v_pk_fma_f32 %4, %8, %14, %4 op_sel:[1,0,0] op_sel_hi:[1,1,1]\n\t"
        "v_pk_fma_f32 %5, %8, %15, %5 op_sel:[1,0,0] op_sel_hi:[1,1,1]\n\t"
        "v_pk_fma_f32 %0, %6, %10, %0 op_sel:[0,0,0] op_sel_hi:[0,1,1]\n\t"
        "v_pk_fma_f32 %1, %6, %11, %1 op_sel:[0,0,0] op_sel_hi:[0,1,1]\n\t"
        "v_pk_fma_f32 %2, %6, %12, %2 op_sel:[0,0,0] op_sel_hi:[0,1,1]\n\t"
        "v_pk_fma_f32 %3, %8, %10, %3 op_sel:[0,0,0] op_sel_hi:[0,1,1]\n\t"
        "v_pk_fma_f32 %4, %8, %11, %4 op_sel:[0,0,0] op_sel_hi:[0,1,1]\n\t"
        "v_pk_fma_f32 %5, %8, %12, %5 op_sel:[0,0,0] op_sel_hi:[0,1,1]"
        : "=&v"(A0), "=&v"(A1), "=&v"(A2), "=&v"(B0), "=&v"(B1), "=&v"(B2)
        : "v"(qa01), "v"(qa23), "v"(qb01), "v"(qb23),
          "v"(c0a), "v"(c0b), "v"(c0c),
          "v"(c1a), "v"(c1b), "v"(c1c),
          "v"(c2a), "v"(c2b), "v"(c2c));
    dmp[0] = fminf(fminf(A0.x, B0.x), dmp[0]);
    dmp[1] = fminf(fminf(A0.y, B0.y), dmp[1]);
    dmp[2] = fminf(fminf(A1.x, B1.x), dmp[2]);
    dmp[3] = fminf(fminf(A1.y, B1.y), dmp[3]);
    dmp[4] = fminf(fminf(A2.x, B2.x), dmp[4]);
    dmp[5] = fminf(fminf(A2.y, B2.y), dmp[5]);
}

// ---------------------------------------------------------------- fused kernel
// R11 = R10 with ONE change: lane-parity model fetch. Each step issues a single
// ds_read_b128 (even lanes read model m, odd lanes m+1 -- 16 addrs, 2 per
// bank-quad = free 2-way); the partner model comes via 4x v_mov_dpp
// quad_perm:[1,0,3,2] (pure VALU, no LDS pipe). min(A,B) is commutative, so
// even/odd lanes processing the pair in swapped order is bit-identical.
// Targets the measured 43% non-issue stall (exposed ds_read latency events).
__global__ __launch_bounds__(TPB, 3) void chamfer_one(
    const float* __restrict__ state, const float* __restrict__ model,
    const float* __restrict__ vis, const float* __restrict__ tac,
    const float* __restrict__ phys, const float* __restrict__ dts,
    float* __restrict__ out) {
    __shared__ v4f   feat[NG * FS];         // 16.9 KB model features {-2g, |g|^2}
    __shared__ float sdm[PTSB][NG + 1];     // 12.7 KB per-point per-group mins (+1 pad)
    __shared__ float sw[2];

    const int t  = threadIdx.x;
    const int g  = t >> 3;                  // model group 0..31
    const int m0 = t & 7;
    const int pl = t & 7;                   // point-lane 0..7 (12 points each)
    const int f  = (blockIdx.x * PTSB) / PPF_;          // block-uniform
    const int lbase = blockIdx.x * PTSB - f * PPF_;

    // ---- stage chunk 0 early (hide under pose math) ----
#pragma unroll
    for (int j2 = 0; j2 < 4; ++j2) {
        int id = g * MPG + m0 + 8 * j2;
        float gx = model[id * 3 + 0], gy = model[id * 3 + 1], gz = model[id * 3 + 2];
        feat[g * FS + m0 + 8 * j2] =
            (v4f){-2.0f * gx, -2.0f * gy, -2.0f * gz, gx * gx + gy * gy + gz * gz};
    }

    // ---- pose for frame f, per-thread (uniform f -> no divergence; identical
    // op order to the reference scan) ----
    float R[9], tr[3];
    {
        tr[0] = state[0]; tr[1] = state[1]; tr[2] = state[2];
        rot_from_omega(state[3], state[4], state[5], 1.0f, R);
        for (int i = 1; i <= f; ++i) {
            float dt = dts[i];
            tr[0] += phys[i * 12 + 6] * dt;
            tr[1] += phys[i * 12 + 7] * dt;
            tr[2] += phys[i * 12 + 8] * dt;
            float Rs[9];
            rot_from_omega(phys[i * 12 + 9], phys[i * 12 + 10], phys[i * 12 + 11], dt, Rs);
            float Rn[9];
            for (int r = 0; r < 3; ++r)
                for (int c2 = 0; c2 < 3; ++c2)
                    Rn[r * 3 + c2] = Rs[r * 3 + 0] * R[0 + c2] +
                                     Rs[r * 3 + 1] * R[3 + c2] +
                                     Rs[r * 3 + 2] * R[6 + c2];
            for (int j = 0; j < 9; ++j) R[j] = Rn[j];
        }
        for (int j = 0; j < 9; ++j) R[j] *= SCALE_INV;  // fold 1/SCALE
    }

    // ---- transform my 12 points into 6 packed pairs ----
    v2f c0p[NPR], c1p[NPR], c2p[NPR];
    float cn[PPL], dm[PPL];
#pragma unroll
    for (int k = 0; k < PPL; ++k) {
        int loc = lbase + pl * PPL + k;
        const float* p = (loc < NV_) ? (vis + ((size_t)f * NV_ + loc) * 3)
                                     : (tac + ((size_t)f * NT_ + (loc - NV_)) * 3);
        float d0 = p[0] - tr[0], d1 = p[1] - tr[1], d2 = p[2] - tr[2];
        float x = d0 * R[0] + d1 * R[3] + d2 * R[6];
        float y = d0 * R[1] + d1 * R[4] + d2 * R[7];
        float z = d0 * R[2] + d1 * R[5] + d2 * R[8];
        cn[k] = x * x + y * y + z * z;
        dm[k] = 3.4e38f;
        if (k & 1) { c0p[k >> 1].y = x; c1p[k >> 1].y = y; c2p[k >> 1].y = z; }
        else       { c0p[k >> 1].x = x; c1p[k >> 1].x = y; c2p[k >> 1].x = z; }
    }
    __syncthreads();

    // ---- main loop: 4 chunks x 32 models/group; one b128/step + DPP partner ----
    const int par = t & 1;                  // lane parity within the quad
    for (int c = 0; c < NCH; ++c) {
        float mx[4], my[4], mz[4];
        if (c + 1 < NCH) {                  // issue next chunk's loads first
#pragma unroll
            for (int j2 = 0; j2 < 4; ++j2) {
                int id = g * MPG + (c + 1) * CHM + m0 + 8 * j2;
                mx[j2] = model[id * 3 + 0];
                my[j2] = model[id * 3 + 1];
                mz[j2] = model[id * 3 + 2];
            }
        }
        const v4f* fb = &feat[g * FS];
#pragma unroll 4
        for (int m = 0; m < CHM; m += 2) {
            v4f fm = fb[m + par];           // 16 addrs/wave, 2 per quad = free
            // partner model via quad_perm [1,0,3,2] (lane 0<->1, 2<->3): VALU only
            v4f pt;
            pt.x = __int_as_float(__builtin_amdgcn_mov_dpp(
                       __float_as_int(fm.x), 0xB1, 0xF, 0xF, true));
            pt.y = __int_as_float(__builtin_amdgcn_mov_dpp(
                       __float_as_int(fm.y), 0xB1, 0xF, 0xF, true));
            pt.z = __int_as_float(__builtin_amdgcn_mov_dpp(
                       __float_as_int(fm.z), 0xB1, 0xF, 0xF, true));
            pt.w = __int_as_float(__builtin_amdgcn_mov_dpp(
                       __float_as_int(fm.w), 0xB1, 0xF, 0xF, true));
            v2f qa01 = (v2f){fm.x, fm.y}, qa23 = (v2f){fm.z, fm.w};
            v2f qb01 = (v2f){pt.x, pt.y}, qb23 = (v2f){pt.z, pt.w};
            dist6(qa01, qa23, qb01, qb23, c0p[0], c0p[1], c0p[2],
                  c1p[0], c1p[1], c1p[2], c2p[0], c2p[1], c2p[2], dm);
            dist6(qa01, qa23, qb01, qb23, c0p[3], c0p[4], c0p[5],
                  c1p[3], c1p[4], c1p[5], c2p[3], c2p[4], c2p[5], dm + 6);
        }
        __syncthreads();                    // all reads of chunk c done
        if (c + 1 < NCH) {
#pragma unroll
            for (int j2 = 0; j2 < 4; ++j2) {
                feat[g * FS + m0 + 8 * j2] =
                    (v4f){-2.0f * mx[j2], -2.0f * my[j2], -2.0f * mz[j2],
                          mx[j2] * mx[j2] + my[j2] * my[j2] + mz[j2] * mz[j2]};
            }
            __syncthreads();                // chunk c+1 staged
        }
    }

    // ---- combine 32 group-partials per point, weight, block-sum, one atomic ----
#pragma unroll
    for (int k = 0; k < PPL; ++k) sdm[pl * PPL + k][g] = dm[k] + cn[k];
    __syncthreads();

    float v = 0.0f;
    if (t < PTSB) {
        const float* row = sdm[t];
        float mn = row[0];
#pragma unroll
        for (int i = 1; i < NG; ++i) mn = fminf(mn, row[i]);
        const int loc = lbase + t;
        const float w = (loc < NV_) ? (1.0f / NV_) : (0.1f / NT_);
        v = mn * w;
    }
    if (t < 128) {
#pragma unroll
        for (int off = 32; off > 0; off >>= 1) v += __shfl_down(v, off);
        if ((t & 63) == 0) sw[t >> 6] = v;
    }
    __syncthreads();
    if (t == 0) atomicAdd(out, sw[0] + sw[1]);
}

// ---------------------------------------------------------------- launch
// d_ws unused: single fused kernel (multi-kernel structures consistently lost
// to launch overhead, r8/r9); the 256MB ws poison fill runs unconditionally.
extern "C" void kernel_launch(void* const* d_in, const int* in_sizes, int n_in,
                              void* d_out, int out_size, void* d_ws, size_t ws_size,
                              hipStream_t stream) {
    const float* state = (const float*)d_in[0];   // (6,)
    const float* model = (const float*)d_in[1];   // (M,3)
    const float* vis   = (const float*)d_in[2];   // (F,NV,3)
    const float* tac   = (const float*)d_in[3];   // (F,NT,3)
    const float* phys  = (const float*)d_in[4];   // (F,12)
    const float* dts   = (const float*)d_in[5];   // (F,)
    float* out = (float*)d_out;
    (void)d_ws; (void)ws_size;

    hipMemsetAsync(out, 0, sizeof(float), stream);
    chamfer_one<<<NBLK, TPB, 0, stream>>>(state, model, vis, tac, phys, dts, out);
}